// Round 8
// baseline (523.034 us; speedup 1.0000x reference)
//
#include <hip/hip_runtime.h>
#include <hip/hip_cooperative_groups.h>

namespace cg = cooperative_groups;

#define KG 20
#define N1 400
#define N2 760
#define BATCH 4096
#define NITER 50

typedef __attribute__((ext_vector_type(8))) short bf16x8;
typedef __attribute__((ext_vector_type(4))) float f32x4;

// Pure compiler barrier: orders the LDS ops in the instruction stream but emits
// NO s_waitcnt. Intra-wave DS ops execute in program order; the compiler still
// auto-inserts lgkmcnt waits before read results are consumed.
#define CBAR() asm volatile("" ::: "memory")

__device__ __forceinline__ float bf2f(unsigned short u) {
    unsigned int x = ((unsigned int)u) << 16;
    union { unsigned int i; float f; } c; c.i = x; return c.f;
}
__device__ __forceinline__ unsigned short f2bf(float f) {
    union { float f; unsigned int i; } c; c.f = f;
    unsigned int r = c.i + 0x7FFFu + ((c.i >> 16) & 1u);  // RNE
    return (unsigned short)(r >> 16);
}
// HW packed f32->bf16 (RNE, same result as f2bf for finite values).
__device__ __forceinline__ unsigned pk_bf16(float lo, float hi) {
    unsigned r;
    asm("v_cvt_pk_bf16_f32 %0, %1, %2" : "=v"(r) : "v"(lo), "v"(hi));
    return r;
}

// ---------------- compile-time DCT-II tables -----------------------------------
constexpr double CPI = 3.14159265358979323846;
constexpr double ccos(double x) {
    constexpr double TP = 6.28318530717958647692;
    long long k = (long long)(x / TP);
    double r = x - (double)k * TP;
    if (r > CPI)  r -= TP;
    if (r < -CPI) r += TP;
    double r2 = r * r, term = 1.0, s = 1.0;
    for (int n = 1; n <= 15; ++n) { term *= -r2 / ((2.0 * n - 1.0) * (2.0 * n)); s += term; }
    return s;
}
struct Tbl { float phi[10][20]; float lam[20]; };   // rows 0..9 only (fold symmetry)
constexpr Tbl mk_tbl() {
    Tbl t{};
    for (int i = 0; i < 10; ++i)
        for (int a = 0; a < 20; ++a) {
            double na = (a == 0) ? 0.22360679774997896964 : 0.31622776601683793320;
            t.phi[i][a] = (float)(na * ccos(CPI * (double)a * ((double)i + 0.5) / 20.0));
        }
    for (int a = 0; a < 20; ++a) t.lam[a] = (float)(2.0 - 2.0 * ccos(CPI * (double)a / 20.0));
    return t;
}
static constexpr Tbl TB = mk_tbl();

__device__ __forceinline__ int detect_flag(const float* beqf) {
    float v = beqf[0];
    return (v > 0.5f && v < 1.5f) ? 0 : 1;   // 0 = fp32 inputs, 1 = bf16 inputs
}

// ---------------- fused MLP: cvt + gemm1 + gemm2 in ONE cooperative kernel -----
// R8 theory: the ~95us non-admm slice is insensitive to GEMM tiling (128x64/
// 128x128/64x64 -> 96/110/96us) while hand-arithmetic puts GEMM compute at
// ~25-40us -> suspect ~50-60us of per-dispatch fixed cost across the 4 serial
// dependent launches. Fuse the 3 MLP dispatches into one cooperative kernel
// with grid.sync() phase barriers (device-scope, cross-XCD-safe per G16).
// 512 blocks x 256 thr (2/CU); gemm1 = 1024 64x64 tiles (2/block), gemm2 =
// 768 (1-2/block). W2 pre-converted in phase A (workspace is 256MB) -> both
// GEMM phases pure bf16. pk_bf16 == in-loop RNE -> bit-identical outputs.

template<bool LEAKY>
__device__ __forceinline__ void gemm_tiles(
        const unsigned short* __restrict__ A,
        const unsigned short* __restrict__ Bm,
        const void* __restrict__ biasRaw,
        unsigned short* __restrict__ C,
        int M, int N, int K, int f,
        unsigned short* As, unsigned short* Bs, int bId, int tid) {
    const int tn   = (N + 63) >> 6;
    const int ttot = (M >> 6) * tn;
    const int wave = tid >> 6, lane = tid & 63;
    const int wm   = (wave & 1) * 32, wn = (wave >> 1) * 32;
    const int fr   = lane & 15;
    const int kc   = (lane >> 4) * 8;
    const int ra   = tid >> 2, ca = (tid & 3) * 8;

    for (int t = bId; t < ttot; t += 512) {
        const int m0  = (t / tn) * 64;
        const int n0  = (t % tn) * 64;
        const int rbg = (n0 + ra < N) ? (n0 + ra) : (N - 1);
        const size_t abase = (size_t)(m0 + ra) * K + ca;
        const size_t bbase = (size_t)rbg * K + ca;

        uint4 av = *(const uint4*)&A[abase];
        uint4 bv = *(const uint4*)&Bm[bbase];

        f32x4 acc[2][2];
#pragma unroll
        for (int a = 0; a < 2; a++)
#pragma unroll
            for (int b = 0; b < 2; b++) acc[a][b] = (f32x4){0.f, 0.f, 0.f, 0.f};

        for (int k0 = 0; k0 < K; k0 += 32) {
            __syncthreads();                       // prior readers done (tile & step)
            *(uint4*)&As[ra * 34 + ca] = av;
            *(uint4*)&Bs[ra * 34 + ca] = bv;
            __syncthreads();

            int kn = (k0 + 32 < K) ? (k0 + 32) : k0;
            av = *(const uint4*)&A[abase + kn];
            bv = *(const uint4*)&Bm[bbase + kn];

            bf16x8 af[2], bfm[2];
#pragma unroll
            for (int a = 0; a < 2; a++) af[a]  = *(const bf16x8*)&As[(wm + a * 16 + fr) * 34 + kc];
#pragma unroll
            for (int b = 0; b < 2; b++) bfm[b] = *(const bf16x8*)&Bs[(wn + b * 16 + fr) * 34 + kc];
#pragma unroll
            for (int a = 0; a < 2; a++)
#pragma unroll
                for (int b = 0; b < 2; b++)
                    acc[a][b] = __builtin_amdgcn_mfma_f32_16x16x32_bf16(af[a], bfm[b], acc[a][b], 0, 0, 0);
        }
        __syncthreads();                           // protect smem before next tile
#pragma unroll
        for (int a = 0; a < 2; a++)
#pragma unroll
            for (int b = 0; b < 2; b++) {
                int col = n0 + wn + b * 16 + (lane & 15);
                if (col < N) {
                    float bs = f ? bf2f(((const unsigned short*)biasRaw)[col])
                                 : ((const float*)biasRaw)[col];
#pragma unroll
                    for (int r = 0; r < 4; r++) {
                        int row = m0 + wm + a * 16 + (lane >> 4) * 4 + r;
                        float v = acc[a][b][r] + bs;
                        if (LEAKY) v = v >= 0.f ? v : 0.1f * v;
                        C[(size_t)row * N + col] = f2bf(v);
                    }
                }
            }
    }
}

__global__ __launch_bounds__(256, 2) void mlp_fused(
        const void* dRaw, const void* w1Raw, const void* w2Raw,
        const void* b1Raw, const void* b2Raw,
        unsigned short* d_bf, unsigned short* w1_bf, unsigned short* w2_bf,
        unsigned short* h_bf, unsigned short* w_bf,
        const float* beqf) {
    __shared__ unsigned short As[64 * 34];
    __shared__ unsigned short Bs[64 * 34];
    const int f   = detect_flag(beqf);
    const int tid = threadIdx.x;
    const int b   = blockIdx.x;

    // ---- phase A: one-time bf16 conversion of d, W1, W2 (flag=1: plain copy)
    {
        const int nv0 = (4096 * 512) / 4;          // d
        const int nv1 = (1024 * 512) / 4;          // W1
        const int nv2 = (760 * 1024) / 4;          // W2
        const int total = nv0 + nv1 + nv2;
        for (int idx = b * 256 + tid; idx < total; idx += 512 * 256) {
            const void* s; unsigned short* dst; int k;
            if (idx < nv0)             { s = dRaw;  dst = d_bf;  k = idx; }
            else if (idx < nv0 + nv1)  { s = w1Raw; dst = w1_bf; k = idx - nv0; }
            else                       { s = w2Raw; dst = w2_bf; k = idx - nv0 - nv1; }
            if (f) {
                ((uint2*)dst)[k] = ((const uint2*)s)[k];
            } else {
                float4 v = ((const float4*)s)[k];
                uint2 p; p.x = pk_bf16(v.x, v.y); p.y = pk_bf16(v.z, v.w);
                ((uint2*)dst)[k] = p;
            }
        }
    }
    cg::this_grid().sync();
    // ---- phase B: h = leaky(d @ W1^T + b1)
    gemm_tiles<true >(d_bf, w1_bf, b1Raw, h_bf, 4096, 1024, 512,  f, As, Bs, b, tid);
    cg::this_grid().sync();
    // ---- phase C: w = h @ W2^T + b2
    gemm_tiles<false>(h_bf, w2_bf, b2Raw, w_bf, 4096, 760,  1024, f, As, Bs, b, tid);
}

// ---------------- fused 50-iteration ADMM: 3 samples/wave (R4-exact, FROZEN) ---
// 5 rounds of probes (shfl, VGPR pin, SGPR pin, f2 packing) all regressed or
// were neutral. Equilibrium: per-wave issue I ~ 242k cyc; 342 of 1024 SIMDs
// carry 2 waves -> critical path ~ 2I + joint stalls ~ 550k cyc ~ 229us.
// 1-wave/SIMD regimes run chain-latency-limited (~2.4I, R5) -> no better.
// Do not touch.
#define SREG 448
__global__ __launch_bounds__(64, 1) void admm_kernel(
        const unsigned short* __restrict__ wglob,
        void* __restrict__ out, const float* __restrict__ beqf) {
    __shared__ float buf[3 * SREG];                // 5376 B

    const int lane = threadIdx.x;
    const int q    = (lane >= 40) ? 2 : (lane >= 20 ? 1 : 0);
    const int i    = lane - 20 * q;
    const int sample = blockIdx.x * 3 + q;
    const int flag = detect_flag(beqf);

    if (lane < 60 && sample < BATCH) {
        float* B = &buf[q * SREG];
        const size_t gb = (size_t)sample * N2;

        float wh[20], wv[20];
        if (i < 19) {
#pragma unroll
            for (int j = 0; j < 19; ++j) {
                wh[j] = bf2f(wglob[gb + 39 * i + 2 * j]);
                wv[j] = bf2f(wglob[gb + 39 * i + 2 * j + 1]);
            }
            wh[19] = 0.f;
            wv[19] = bf2f(wglob[gb + 39 * i + 38]);
        } else {
#pragma unroll
            for (int j = 0; j < 19; ++j) { wh[j] = bf2f(wglob[gb + 741 + j]); wv[j] = 0.f; }
            wh[19] = 0.f; wv[19] = 0.f;
        }

        float g[20];
        {
            float lamB = TB.lam[i];
#pragma unroll
            for (int a = 0; a < 20; ++a) g[a] = 1.f / (TB.lam[a] + lamB);
            if (i == 0) g[0] = 0.f;   // zero mode (0,0)
        }

        float sh[20], sv[20];
#pragma unroll
        for (int j = 0; j < 20; ++j) { sh[j] = 0.f; sv[j] = 0.f; }

        const int rup = (i > 0)  ? i - 1 : 0;
        const int rdn = (i < 19) ? i + 1 : i;

#pragma unroll 1
        for (int it = 0; it < NITER; ++it) {
            float vh[20], vv[20];
#pragma unroll
            for (int j = 0; j < 20; ++j) {
                vh[j] = fabsf(sh[j]) - wh[j];
                vv[j] = fabsf(sv[j]) - wv[j];
            }
#pragma unroll
            for (int j = 0; j < 20; j += 4)
                *(f32x4*)&B[20 * i + j] = (f32x4){vv[j], vv[j + 1], vv[j + 2], vv[j + 3]};
            CBAR();
            float vvUp[20];
#pragma unroll
            for (int j = 0; j < 20; j += 4) {
                f32x4 t = *(f32x4*)&B[20 * rup + j];
                vvUp[j] = t[0]; vvUp[j + 1] = t[1]; vvUp[j + 2] = t[2]; vvUp[j + 3] = t[3];
            }
            CBAR();
            float r[20];
#pragma unroll
            for (int j = 0; j < 20; ++j) {
                float acc = ((j < 19) ? vh[j] : 0.f) + vv[j];
                if (j > 0) acc -= vh[j - 1];
                acc -= (i > 0) ? vvUp[j] : 0.f;
                r[j] = acc;
            }
            r[0]  -= (i == 0)  ? 2.f : 0.f;
            r[19] += (i == 19) ? 2.f : 0.f;

            // ---- fold rows ----
            float e[10], o[10];
#pragma unroll
            for (int jj = 0; jj < 10; ++jj) { e[jj] = r[jj] + r[19 - jj]; o[jj] = r[jj] - r[19 - jj]; }
            // ---- T1[b] = folded row-DCT; transpose-1 store (stride 22) ----
#pragma unroll
            for (int b = 0; b < 20; ++b) {
                float a;
                if ((b & 1) == 0) {
                    a = e[0] * TB.phi[0][b];
#pragma unroll
                    for (int jj = 1; jj < 10; ++jj) a += e[jj] * TB.phi[jj][b];
                } else {
                    a = o[0] * TB.phi[0][b];
#pragma unroll
                    for (int jj = 1; jj < 10; ++jj) a += o[jj] * TB.phi[jj][b];
                }
                B[22 * b + i] = a;
            }
            CBAR();
            float t2[20];
#pragma unroll
            for (int k = 0; k < 20; k += 2) {
                float2 p = *(const float2*)&B[22 * i + k];
                t2[k] = p.x; t2[k + 1] = p.y;
            }
            CBAR();
            // ---- fold; U[a] = col-DCT; scale by g ----
            float e2[10], o2[10];
#pragma unroll
            for (int kk = 0; kk < 10; ++kk) { e2[kk] = t2[kk] + t2[19 - kk]; o2[kk] = t2[kk] - t2[19 - kk]; }
            float v2[20];
#pragma unroll
            for (int a = 0; a < 20; ++a) {
                float acc;
                if ((a & 1) == 0) {
                    acc = e2[0] * TB.phi[0][a];
#pragma unroll
                    for (int kk = 1; kk < 10; ++kk) acc += e2[kk] * TB.phi[kk][a];
                } else {
                    acc = o2[0] * TB.phi[0][a];
#pragma unroll
                    for (int kk = 1; kk < 10; ++kk) acc += o2[kk] * TB.phi[kk][a];
                }
                v2[a] = acc * g[a];
            }
            // ---- Y rows (output-pair folded); transpose-2 store ----
#pragma unroll
            for (int II = 0; II < 10; ++II) {
                float E = v2[0] * TB.phi[II][0];
#pragma unroll
                for (int m = 1; m < 10; ++m) E += v2[2 * m] * TB.phi[II][2 * m];
                float O = v2[1] * TB.phi[II][1];
#pragma unroll
                for (int m = 1; m < 10; ++m) O += v2[2 * m + 1] * TB.phi[II][2 * m + 1];
                B[22 * II + i]        = E + O;
                B[22 * (19 - II) + i] = E - O;
            }
            CBAR();
            float t3[20];
#pragma unroll
            for (int b = 0; b < 20; b += 2) {
                float2 p = *(const float2*)&B[22 * i + b];
                t3[b] = p.x; t3[b + 1] = p.y;
            }
            CBAR();
            // ---- nu rows (output-pair folded) ----
            float nu[20];
#pragma unroll
            for (int JJ = 0; JJ < 10; ++JJ) {
                float E = t3[0] * TB.phi[JJ][0];
#pragma unroll
                for (int m = 1; m < 10; ++m) E += t3[2 * m] * TB.phi[JJ][2 * m];
                float O = t3[1] * TB.phi[JJ][1];
#pragma unroll
                for (int m = 1; m < 10; ++m) O += t3[2 * m + 1] * TB.phi[JJ][2 * m + 1];
                nu[JJ]      = E + O;
                nu[19 - JJ] = E - O;
            }
#pragma unroll
            for (int j = 0; j < 20; j += 4)
                *(f32x4*)&B[20 * i + j] = (f32x4){nu[j], nu[j + 1], nu[j + 2], nu[j + 3]};
            CBAR();
            float nuDn[20];
#pragma unroll
            for (int j = 0; j < 20; j += 4) {
                f32x4 t = *(f32x4*)&B[20 * rdn + j];
                nuDn[j] = t[0]; nuDn[j + 1] = t[1]; nuDn[j + 2] = t[2]; nuDn[j + 3] = t[3];
            }
            CBAR();
#pragma unroll
            for (int j = 0; j < 20; ++j) {
                float xv = 0.5f * (vv[j] - nu[j] + nuDn[j]);
                sv[j] = xv + fminf(sv[j], 0.f);
                float xh = 0.f;
                if (j < 19) {
                    xh = 0.5f * (vh[j] - nu[j] + nu[j + 1]);
                    sh[j] = xh + fminf(sh[j], 0.f);
                }
                if (it == NITER - 1) {
                    if (i < 19) {
                        if (j < 19) {
                            if (flag) {
                                ((unsigned short*)out)[gb + 39 * i + 2 * j]     = f2bf(xh);
                                ((unsigned short*)out)[gb + 39 * i + 2 * j + 1] = f2bf(xv);
                            } else {
                                ((float*)out)[gb + 39 * i + 2 * j]     = xh;
                                ((float*)out)[gb + 39 * i + 2 * j + 1] = xv;
                            }
                        } else {
                            if (flag) ((unsigned short*)out)[gb + 39 * i + 38] = f2bf(xv);
                            else      ((float*)out)[gb + 39 * i + 38] = xv;
                        }
                    } else if (j < 19) {
                        if (flag) ((unsigned short*)out)[gb + 741 + j] = f2bf(xh);
                        else      ((float*)out)[gb + 741 + j] = xh;
                    }
                }
            }
        }
    }
}

extern "C" void kernel_launch(void* const* d_in, const int* in_sizes, int n_in,
                              void* d_out, int out_size, void* d_ws, size_t ws_size,
                              hipStream_t stream) {
    (void)in_sizes; (void)n_in; (void)out_size; (void)ws_size;
    const void*  d   = d_in[0];
    const void*  W1  = d_in[1];
    const void*  b1  = d_in[2];
    const void*  W2  = d_in[3];
    const void*  b2  = d_in[4];
    const float* beq = (const float*)d_in[6];   // A (d_in[5]) unused: closed-form

    char* ws = (char*)d_ws;
    // Workspace layout (disjoint; ws is 256 MB per the warmup memset):
    //   h_bf  @ 0        : 4096x1024 bf16 = 8388608 B
    //   w_bf  @ 8388608  : 4096x760  bf16 = 6225920 B
    //   d_bf  @ 16777216 : 4096x512  bf16 = 4194304 B
    //   w1_bf @ 20971520 : 1024x512  bf16 = 1048576 B
    //   w2_bf @ 22020096 : 760x1024  bf16 = 1556480 B
    unsigned short* h_bf  = (unsigned short*)(ws);
    unsigned short* w_bf  = (unsigned short*)(ws + 8388608);
    unsigned short* d_bf  = (unsigned short*)(ws + 16777216);
    unsigned short* w1_bf = (unsigned short*)(ws + 20971520);
    unsigned short* w2_bf = (unsigned short*)(ws + 22020096);

    void* kargs[] = { (void*)&d, (void*)&W1, (void*)&W2, (void*)&b1, (void*)&b2,
                      (void*)&d_bf, (void*)&w1_bf, (void*)&w2_bf,
                      (void*)&h_bf, (void*)&w_bf, (void*)&beq };
    hipLaunchCooperativeKernel((const void*)mlp_fused, dim3(512), dim3(256),
                               kargs, 0, stream);

    admm_kernel<<<(BATCH + 2) / 3, 64, 0, stream>>>(w_bf, d_out, beq);
}

// Round 9
// 325.152 us; speedup vs baseline: 1.6086x; 1.6086x over previous
//
#include <hip/hip_runtime.h>

#define KG 20
#define N1 400
#define N2 760
#define BATCH 4096
#define NITER 50

typedef __attribute__((ext_vector_type(8))) short bf16x8;
typedef __attribute__((ext_vector_type(4))) float f32x4;

// Pure compiler barrier: orders the LDS ops in the instruction stream but emits
// NO s_waitcnt. Intra-wave DS ops execute in program order; the compiler still
// auto-inserts lgkmcnt waits before read results are consumed.
#define CBAR() asm volatile("" ::: "memory")

__device__ __forceinline__ float bf2f(unsigned short u) {
    unsigned int x = ((unsigned int)u) << 16;
    union { unsigned int i; float f; } c; c.i = x; return c.f;
}
__device__ __forceinline__ unsigned short f2bf(float f) {
    union { float f; unsigned int i; } c; c.f = f;
    unsigned int r = c.i + 0x7FFFu + ((c.i >> 16) & 1u);  // RNE
    return (unsigned short)(r >> 16);
}
// HW packed f32->bf16 (RNE, same result as f2bf for finite values).
__device__ __forceinline__ unsigned pk_bf16(float lo, float hi) {
    unsigned r;
    asm("v_cvt_pk_bf16_f32 %0, %1, %2" : "=v"(r) : "v"(lo), "v"(hi));
    return r;
}

// ---------------- compile-time DCT-II tables -----------------------------------
constexpr double CPI = 3.14159265358979323846;
constexpr double ccos(double x) {
    constexpr double TP = 6.28318530717958647692;
    long long k = (long long)(x / TP);
    double r = x - (double)k * TP;
    if (r > CPI)  r -= TP;
    if (r < -CPI) r += TP;
    double r2 = r * r, term = 1.0, s = 1.0;
    for (int n = 1; n <= 15; ++n) { term *= -r2 / ((2.0 * n - 1.0) * (2.0 * n)); s += term; }
    return s;
}
struct Tbl { float phi[10][20]; float lam[20]; };   // rows 0..9 only (fold symmetry)
constexpr Tbl mk_tbl() {
    Tbl t{};
    for (int i = 0; i < 10; ++i)
        for (int a = 0; a < 20; ++a) {
            double na = (a == 0) ? 0.22360679774997896964 : 0.31622776601683793320;
            t.phi[i][a] = (float)(na * ccos(CPI * (double)a * ((double)i + 0.5) / 20.0));
        }
    for (int a = 0; a < 20; ++a) t.lam[a] = (float)(2.0 - 2.0 * ccos(CPI * (double)a / 20.0));
    return t;
}
static constexpr Tbl TB = mk_tbl();

__device__ __forceinline__ int detect_flag(const float* beqf) {
    float v = beqf[0];
    return (v > 0.5f && v < 1.5f) ? 0 : 1;   // 0 = fp32 inputs, 1 = bf16 inputs
}

// ---------------- MLP GEMM: 64x64 block, in-loop fp32->bf16 conversion ---------
// R9 consolidation (best-of-rounds composition):
//  * 3-dispatch structure (R0): no separate cvt kernel. R0 vs R4 showed in-loop
//    conversion is FREE (slice 92 vs 96us) — conversion VALU hides under the
//    staging stalls of this latency-bound small-K GEMM.
//  * 64x64 tiles, 4 waves 2x2, 4 blocks/CU (R7): slice insensitive to tile size
//    in 64-128 range; 64x64 ties best and has no tail tiles.
//  * pk_bf16 (R4): 2 elems/instr, RNE == f2bf -> bit-identical.
//  * R8 refuted: cooperative fusion costs ~180us (grid.sync >> kernel boundary;
//    per-dispatch overhead is only ~4-5us). Do not fuse.
template<bool LEAKY>
__global__ __launch_bounds__(256) void gemm_bt_bf16(
        const void* __restrict__ A,
        const void* __restrict__ B,
        const void* __restrict__ biasRaw,
        unsigned short* __restrict__ C,
        int M, int N, int K, const float* __restrict__ beqf, int aIsRaw) {
    __shared__ unsigned short As[64 * 34];
    __shared__ unsigned short Bs[64 * 34];
    const int f   = detect_flag(beqf);
    const int aBf = aIsRaw ? f : 1;    // A raw input: fp32 when flag==0
    const int bBf = f;                 // B (weights) always raw input
    const int tid  = threadIdx.x;
    const int m0   = blockIdx.x * 64;
    const int n0   = blockIdx.y * 64;
    const int wave = tid >> 6, lane = tid & 63;
    const int wm   = (wave & 1) * 32, wn = (wave >> 1) * 32;
    const int fr   = lane & 15;
    const int kc   = (lane >> 4) * 8;

    const int ra = tid >> 2, ca = (tid & 3) * 8;       // 64 rows x 32 cols, 8 shorts/thread
    const int rbg = (n0 + ra < N) ? (n0 + ra) : (N - 1);

    uint4 av, bv;
    auto load_tiles = [&](int k0) {
        size_t aoff = (size_t)(m0 + ra) * K + k0 + ca;
        if (aBf) {
            av = *(const uint4*)&((const unsigned short*)A)[aoff];
        } else {
            const float* Af = (const float*)A;
            float4 f0 = *(const float4*)&Af[aoff];
            float4 f1 = *(const float4*)&Af[aoff + 4];
            av.x = pk_bf16(f0.x, f0.y);
            av.y = pk_bf16(f0.z, f0.w);
            av.z = pk_bf16(f1.x, f1.y);
            av.w = pk_bf16(f1.z, f1.w);
        }
        size_t boff = (size_t)rbg * K + k0 + ca;
        if (bBf) {
            bv = *(const uint4*)&((const unsigned short*)B)[boff];
        } else {
            const float* Bf = (const float*)B;
            float4 f0 = *(const float4*)&Bf[boff];
            float4 f1 = *(const float4*)&Bf[boff + 4];
            bv.x = pk_bf16(f0.x, f0.y);
            bv.y = pk_bf16(f0.z, f0.w);
            bv.z = pk_bf16(f1.x, f1.y);
            bv.w = pk_bf16(f1.z, f1.w);
        }
    };

    f32x4 acc[2][2];
#pragma unroll
    for (int a = 0; a < 2; a++)
#pragma unroll
        for (int b = 0; b < 2; b++) acc[a][b] = (f32x4){0.f, 0.f, 0.f, 0.f};

    load_tiles(0);
    for (int k0 = 0; k0 < K; k0 += 32) {
        *(uint4*)&As[ra * 34 + ca] = av;
        *(uint4*)&Bs[ra * 34 + ca] = bv;
        __syncthreads();

        int kn = (k0 + 32 < K) ? (k0 + 32) : k0;
        load_tiles(kn);

        bf16x8 af[2], bfm[2];
#pragma unroll
        for (int a = 0; a < 2; a++) af[a]  = *(const bf16x8*)&As[(wm + a * 16 + fr) * 34 + kc];
#pragma unroll
        for (int b = 0; b < 2; b++) bfm[b] = *(const bf16x8*)&Bs[(wn + b * 16 + fr) * 34 + kc];
#pragma unroll
        for (int a = 0; a < 2; a++)
#pragma unroll
            for (int b = 0; b < 2; b++)
                acc[a][b] = __builtin_amdgcn_mfma_f32_16x16x32_bf16(af[a], bfm[b], acc[a][b], 0, 0, 0);
        __syncthreads();
    }
#pragma unroll
    for (int a = 0; a < 2; a++)
#pragma unroll
        for (int b = 0; b < 2; b++) {
            int col = n0 + wn + b * 16 + (lane & 15);
            if (col < N) {
                float bs = f ? bf2f(((const unsigned short*)biasRaw)[col])
                             : ((const float*)biasRaw)[col];
#pragma unroll
                for (int r = 0; r < 4; r++) {
                    int row = m0 + wm + a * 16 + (lane >> 4) * 4 + r;
                    float v = acc[a][b][r] + bs;
                    if (LEAKY) v = v >= 0.f ? v : 0.1f * v;
                    C[(size_t)row * N + col] = f2bf(v);
                }
            }
        }
}

// ---------------- fused 50-iteration ADMM: 3 samples/wave (R4-exact, FROZEN) ---
// 6 structural probes refuted (shfl exchanges, VGPR pin, SGPR pin, f2 packing,
// and by extension any 1-wave/SIMD regime). Equilibrium: per-wave issue I with
// 1366 waves on 1024 SIMDs -> 342 SIMDs carry 2 waves; their 2I issue +
// residual joint stalls == wall time. Both more samples/wave (fewer waves,
// stalls exposed) and fewer samples/wave (same 2/SIMD ceiling) lose. Do not
// touch.
#define SREG 448
__global__ __launch_bounds__(64, 1) void admm_kernel(
        const unsigned short* __restrict__ wglob,
        void* __restrict__ out, const float* __restrict__ beqf) {
    __shared__ float buf[3 * SREG];                // 5376 B

    const int lane = threadIdx.x;
    const int q    = (lane >= 40) ? 2 : (lane >= 20 ? 1 : 0);
    const int i    = lane - 20 * q;
    const int sample = blockIdx.x * 3 + q;
    const int flag = detect_flag(beqf);

    if (lane < 60 && sample < BATCH) {
        float* B = &buf[q * SREG];
        const size_t gb = (size_t)sample * N2;

        float wh[20], wv[20];
        if (i < 19) {
#pragma unroll
            for (int j = 0; j < 19; ++j) {
                wh[j] = bf2f(wglob[gb + 39 * i + 2 * j]);
                wv[j] = bf2f(wglob[gb + 39 * i + 2 * j + 1]);
            }
            wh[19] = 0.f;
            wv[19] = bf2f(wglob[gb + 39 * i + 38]);
        } else {
#pragma unroll
            for (int j = 0; j < 19; ++j) { wh[j] = bf2f(wglob[gb + 741 + j]); wv[j] = 0.f; }
            wh[19] = 0.f; wv[19] = 0.f;
        }

        float g[20];
        {
            float lamB = TB.lam[i];
#pragma unroll
            for (int a = 0; a < 20; ++a) g[a] = 1.f / (TB.lam[a] + lamB);
            if (i == 0) g[0] = 0.f;   // zero mode (0,0)
        }

        float sh[20], sv[20];
#pragma unroll
        for (int j = 0; j < 20; ++j) { sh[j] = 0.f; sv[j] = 0.f; }

        const int rup = (i > 0)  ? i - 1 : 0;
        const int rdn = (i < 19) ? i + 1 : i;

#pragma unroll 1
        for (int it = 0; it < NITER; ++it) {
            float vh[20], vv[20];
#pragma unroll
            for (int j = 0; j < 20; ++j) {
                vh[j] = fabsf(sh[j]) - wh[j];
                vv[j] = fabsf(sv[j]) - wv[j];
            }
#pragma unroll
            for (int j = 0; j < 20; j += 4)
                *(f32x4*)&B[20 * i + j] = (f32x4){vv[j], vv[j + 1], vv[j + 2], vv[j + 3]};
            CBAR();
            float vvUp[20];
#pragma unroll
            for (int j = 0; j < 20; j += 4) {
                f32x4 t = *(f32x4*)&B[20 * rup + j];
                vvUp[j] = t[0]; vvUp[j + 1] = t[1]; vvUp[j + 2] = t[2]; vvUp[j + 3] = t[3];
            }
            CBAR();
            float r[20];
#pragma unroll
            for (int j = 0; j < 20; ++j) {
                float acc = ((j < 19) ? vh[j] : 0.f) + vv[j];
                if (j > 0) acc -= vh[j - 1];
                acc -= (i > 0) ? vvUp[j] : 0.f;
                r[j] = acc;
            }
            r[0]  -= (i == 0)  ? 2.f : 0.f;
            r[19] += (i == 19) ? 2.f : 0.f;

            // ---- fold rows ----
            float e[10], o[10];
#pragma unroll
            for (int jj = 0; jj < 10; ++jj) { e[jj] = r[jj] + r[19 - jj]; o[jj] = r[jj] - r[19 - jj]; }
            // ---- T1[b] = folded row-DCT; transpose-1 store (stride 22) ----
#pragma unroll
            for (int b = 0; b < 20; ++b) {
                float a;
                if ((b & 1) == 0) {
                    a = e[0] * TB.phi[0][b];
#pragma unroll
                    for (int jj = 1; jj < 10; ++jj) a += e[jj] * TB.phi[jj][b];
                } else {
                    a = o[0] * TB.phi[0][b];
#pragma unroll
                    for (int jj = 1; jj < 10; ++jj) a += o[jj] * TB.phi[jj][b];
                }
                B[22 * b + i] = a;
            }
            CBAR();
            float t2[20];
#pragma unroll
            for (int k = 0; k < 20; k += 2) {
                float2 p = *(const float2*)&B[22 * i + k];
                t2[k] = p.x; t2[k + 1] = p.y;
            }
            CBAR();
            // ---- fold; U[a] = col-DCT; scale by g ----
            float e2[10], o2[10];
#pragma unroll
            for (int kk = 0; kk < 10; ++kk) { e2[kk] = t2[kk] + t2[19 - kk]; o2[kk] = t2[kk] - t2[19 - kk]; }
            float v2[20];
#pragma unroll
            for (int a = 0; a < 20; ++a) {
                float acc;
                if ((a & 1) == 0) {
                    acc = e2[0] * TB.phi[0][a];
#pragma unroll
                    for (int kk = 1; kk < 10; ++kk) acc += e2[kk] * TB.phi[kk][a];
                } else {
                    acc = o2[0] * TB.phi[0][a];
#pragma unroll
                    for (int kk = 1; kk < 10; ++kk) acc += o2[kk] * TB.phi[kk][a];
                }
                v2[a] = acc * g[a];
            }
            // ---- Y rows (output-pair folded); transpose-2 store ----
#pragma unroll
            for (int II = 0; II < 10; ++II) {
                float E = v2[0] * TB.phi[II][0];
#pragma unroll
                for (int m = 1; m < 10; ++m) E += v2[2 * m] * TB.phi[II][2 * m];
                float O = v2[1] * TB.phi[II][1];
#pragma unroll
                for (int m = 1; m < 10; ++m) O += v2[2 * m + 1] * TB.phi[II][2 * m + 1];
                B[22 * II + i]        = E + O;
                B[22 * (19 - II) + i] = E - O;
            }
            CBAR();
            float t3[20];
#pragma unroll
            for (int b = 0; b < 20; b += 2) {
                float2 p = *(const float2*)&B[22 * i + b];
                t3[b] = p.x; t3[b + 1] = p.y;
            }
            CBAR();
            // ---- nu rows (output-pair folded) ----
            float nu[20];
#pragma unroll
            for (int JJ = 0; JJ < 10; ++JJ) {
                float E = t3[0] * TB.phi[JJ][0];
#pragma unroll
                for (int m = 1; m < 10; ++m) E += t3[2 * m] * TB.phi[JJ][2 * m];
                float O = t3[1] * TB.phi[JJ][1];
#pragma unroll
                for (int m = 1; m < 10; ++m) O += t3[2 * m + 1] * TB.phi[JJ][2 * m + 1];
                nu[JJ]      = E + O;
                nu[19 - JJ] = E - O;
            }
#pragma unroll
            for (int j = 0; j < 20; j += 4)
                *(f32x4*)&B[20 * i + j] = (f32x4){nu[j], nu[j + 1], nu[j + 2], nu[j + 3]};
            CBAR();
            float nuDn[20];
#pragma unroll
            for (int j = 0; j < 20; j += 4) {
                f32x4 t = *(f32x4*)&B[20 * rdn + j];
                nuDn[j] = t[0]; nuDn[j + 1] = t[1]; nuDn[j + 2] = t[2]; nuDn[j + 3] = t[3];
            }
            CBAR();
#pragma unroll
            for (int j = 0; j < 20; ++j) {
                float xv = 0.5f * (vv[j] - nu[j] + nuDn[j]);
                sv[j] = xv + fminf(sv[j], 0.f);
                float xh = 0.f;
                if (j < 19) {
                    xh = 0.5f * (vh[j] - nu[j] + nu[j + 1]);
                    sh[j] = xh + fminf(sh[j], 0.f);
                }
                if (it == NITER - 1) {
                    if (i < 19) {
                        if (j < 19) {
                            if (flag) {
                                ((unsigned short*)out)[gb + 39 * i + 2 * j]     = f2bf(xh);
                                ((unsigned short*)out)[gb + 39 * i + 2 * j + 1] = f2bf(xv);
                            } else {
                                ((float*)out)[gb + 39 * i + 2 * j]     = xh;
                                ((float*)out)[gb + 39 * i + 2 * j + 1] = xv;
                            }
                        } else {
                            if (flag) ((unsigned short*)out)[gb + 39 * i + 38] = f2bf(xv);
                            else      ((float*)out)[gb + 39 * i + 38] = xv;
                        }
                    } else if (j < 19) {
                        if (flag) ((unsigned short*)out)[gb + 741 + j] = f2bf(xh);
                        else      ((float*)out)[gb + 741 + j] = xh;
                    }
                }
            }
        }
    }
}

extern "C" void kernel_launch(void* const* d_in, const int* in_sizes, int n_in,
                              void* d_out, int out_size, void* d_ws, size_t ws_size,
                              hipStream_t stream) {
    (void)in_sizes; (void)n_in; (void)out_size; (void)ws_size;
    const void*  d   = d_in[0];
    const void*  W1  = d_in[1];
    const void*  b1  = d_in[2];
    const void*  W2  = d_in[3];
    const void*  b2  = d_in[4];
    const float* beq = (const float*)d_in[6];   // A (d_in[5]) unused: closed-form

    char* ws = (char*)d_ws;
    // Workspace layout:
    //   h_bf @ 0       : 4096x1024 bf16 = 8388608 B   (gemm1 out, gemm2 in)
    //   w_bf @ 8388608 : 4096x760  bf16 = 6225920 B   (gemm2 out, admm in)
    unsigned short* h_bf = (unsigned short*)(ws);
    unsigned short* w_bf = (unsigned short*)(ws + 8388608);

    gemm_bt_bf16<true ><<<dim3(64, 16), 256, 0, stream>>>(d,    W1, b1, h_bf, 4096, 1024, 512,  beq, 1);
    gemm_bt_bf16<false><<<dim3(64, 12), 256, 0, stream>>>(h_bf, W2, b2, w_bf, 4096, 760,  1024, beq, 0);

    admm_kernel<<<(BATCH + 2) / 3, 64, 0, stream>>>(w_bf, d_out, beq);
}